// Round 22
// baseline (18.141 us; speedup 1.0000x reference)
//
#include <hip/hip_runtime.h>
#include <math.h>

#define NG  8
#define DH  8
#define NCP 4     // channel pairs
#define KS  7
#define PAD 3
#define TH  16    // tile rows
#define TW  32    // tile cols
#define OW  2     // outputs per thread along W
#define TPH 22    // padded tile rows
#define RSTW 40   // ci-packed LDS row stride in h2-words (38 cols + 2 pad)
#define PLW  (TPH * RSTW)   // 880 words per cp-plane
#define RST1 20   // j-packed LDS row stride in h2-words (19 col-pairs + 1 pad)
#define PL1  (TPH * RST1)   // 440 words per channel plane
#define CH  64
#define HH  64
#define WW  64

typedef __fp16 h2v __attribute__((ext_vector_type(2)));
typedef __fp16 h4v __attribute__((ext_vector_type(4)));

#if __has_builtin(__builtin_amdgcn_exp2f)
#define EXP2(x) __builtin_amdgcn_exp2f(x)
#else
#define EXP2(x) exp2f(x)
#endif

__device__ __forceinline__ int imin(int a, int b) { return a < b ? a : b; }
__device__ __forceinline__ int imax(int a, int b) { return a > b ? a : b; }

__global__ __launch_bounds__(256, 2)   // cap 128 VGPR (R12-proven)
void saconv_kernel(const float* __restrict__ x,
                   const float* __restrict__ wq,
                   const float* __restrict__ wk,
                   const float* __restrict__ wv,
                   const float* __restrict__ relh,
                   const float* __restrict__ relw,
                   float* __restrict__ out) {
  // ci-packed: xs2[cp*PLW + row*RSTW + col] = h2(x[2cp](col'), x[2cp+1](col'))
  __shared__ h2v xs2[NCP * PLW];        // 14.1 KB
  // j-packed:  xs1[ci*PL1 + row*RST1 + k] = h2(x[ci](2k'), x[ci](2k'+1))
  __shared__ h2v xs1[DH * PL1];         // 14.1 KB
  __shared__ h2v swq2[DH * NCP];
  __shared__ h2v swv2[DH * NCP];
  __shared__ h2v swk2[DH * NCP];        // transposed, sl2e pre-folded
  __shared__ h2v srel2[KS * NCP];       // sl2e pre-folded

  const int tx  = threadIdx.x;          // 0..15 (pair of output columns)
  const int ty  = threadIdx.y;          // 0..15 (output row)
  const int tid = ty * 16 + tx;
  const int bz  = blockIdx.z;
  const int b   = bz >> 3;
  const int g   = bz & 7;
  const int h0  = blockIdx.y * TH;
  const int w0  = blockIdx.x * TW;

  const float sl2e = 0.35355339059327373f * 1.4426950408889634f;  // sqrt(1/8)*log2(e)

  // ---- stage weights as f16 pairs (124 items) ----
  if (tid < 32) {
    int c = tid >> 2, cp = tid & 3;
    swq2[tid] = __builtin_amdgcn_cvt_pkrtz(wq[g * 64 + c * 8 + 2 * cp],
                                           wq[g * 64 + c * 8 + 2 * cp + 1]);
  } else if (tid < 64) {
    int t2 = tid - 32;
    int c = t2 >> 2, cp = t2 & 3;
    swv2[t2] = __builtin_amdgcn_cvt_pkrtz(wv[g * 64 + c * 8 + 2 * cp],
                                          wv[g * 64 + c * 8 + 2 * cp + 1]);
  } else if (tid < 96) {
    int t2 = tid - 64;
    int ci = t2 >> 2, cP = t2 & 3;
    swk2[t2] = __builtin_amdgcn_cvt_pkrtz(wk[g * 64 + (2 * cP) * 8 + ci] * sl2e,
                                          wk[g * 64 + (2 * cP + 1) * 8 + ci] * sl2e);
  } else if (tid < 96 + KS * NCP) {
    int t2 = tid - 96;
    int t = t2 >> 2, cP = t2 & 3;
    float a0, a1;
    if (g < 4) {
      a0 = relh[(g * 8 + 2 * cP) * KS + t];
      a1 = relh[(g * 8 + 2 * cP + 1) * KS + t];
    } else {
      a0 = relw[((g - 4) * 8 + 2 * cP) * KS + t];
      a1 = relw[((g - 4) * 8 + 2 * cP + 1) * KS + t];
    }
    srel2[t2] = __builtin_amdgcn_cvt_pkrtz(a0 * sl2e, a1 * sl2e);
  }

  // ---- stage zero-padded x tile: BOTH layouts from the same loaded values ----
  const float* xb = x + (size_t)(b * CH + g * DH) * (HH * WW);
  const int NCHK = NCP * TPH * 19;      // 1672 chunks (col pairs 0..18)
  #pragma unroll
  for (int kk = 0; kk < 7; kk++) {
    int f = tid + kk * 256;
    if (f < NCHK) {
      int cp  = f / (TPH * 19);
      int r   = f - cp * (TPH * 19);
      int row = r / 19;
      int cc  = r - row * 19;
      int yy  = h0 + row - PAD;
      int cy  = imin(imax(yy, 0), HH - 1);
      bool yok = (yy >= 0) & (yy < HH);
      const float* p0 = xb + ((size_t)(2 * cp) * HH + cy) * WW;
      float v0[2], v1[2];
      #pragma unroll
      for (int e = 0; e < 2; e++) {
        int xx = w0 + 2 * cc + e - PAD;
        int cx = imin(imax(xx, 0), WW - 1);
        bool inb = yok & (xx >= 0) & (xx < WW);
        float a0 = p0[cx];
        float a1 = p0[HH * WW + cx];
        v0[e] = inb ? a0 : 0.0f;
        v1[e] = inb ? a1 : 0.0f;
      }
      // ci-packed (logit path)
      h2v pk0 = __builtin_amdgcn_cvt_pkrtz(v0[0], v1[0]);
      h2v pk1 = __builtin_amdgcn_cvt_pkrtz(v0[1], v1[1]);
      h4v w4 = { pk0.x, pk0.y, pk1.x, pk1.y };
      *(h4v*)&xs2[cp * PLW + row * RSTW + 2 * cc] = w4;
      // j-packed (accum path): pair of consecutive cols per channel
      xs1[(2 * cp) * PL1 + row * RST1 + cc]     = __builtin_amdgcn_cvt_pkrtz(v0[0], v0[1]);
      xs1[(2 * cp + 1) * PL1 + row * RST1 + cc] = __builtin_amdgcn_cvt_pkrtz(v1[0], v1[1]);
    }
  }
  __syncthreads();

  // ---- T5 (R20 win) ----
  __builtin_amdgcn_s_setprio(1);

  // ---- preamble, all fdot2 (R16-verbatim except rq -= 8 shift) ----
  h2v  qkh[OW][NCP];
  float rq[OW][KS];
  {
    h2v xc2[OW][NCP];
    #pragma unroll
    for (int o = 0; o < OW; o++)
      #pragma unroll
      for (int cp = 0; cp < NCP; cp++)
        xc2[o][cp] = xs2[cp * PLW + (ty + PAD) * RSTW + (2 * tx + o + PAD)];

    #pragma unroll
    for (int o = 0; o < OW; o++) {
      float q_[DH];
      #pragma unroll
      for (int c = 0; c < DH; c++) {
        float a = 0.f;
        #pragma unroll
        for (int cp = 0; cp < NCP; cp++)
          a = __builtin_amdgcn_fdot2(swq2[c * 4 + cp], xc2[o][cp], a, false);
        q_[c] = a;
      }
      h2v qp[NCP];
      #pragma unroll
      for (int cP = 0; cP < NCP; cP++)
        qp[cP] = __builtin_amdgcn_cvt_pkrtz(q_[2 * cP], q_[2 * cP + 1]);

      float qkt[DH];
      #pragma unroll
      for (int ci = 0; ci < DH; ci++) {
        float a = 0.f;
        #pragma unroll
        for (int cP = 0; cP < NCP; cP++)
          a = __builtin_amdgcn_fdot2(qp[cP], swk2[ci * 4 + cP], a, false);
        qkt[ci] = a;
      }
      #pragma unroll
      for (int cp = 0; cp < NCP; cp++)
        qkh[o][cp] = __builtin_amdgcn_cvt_pkrtz(qkt[2 * cp], qkt[2 * cp + 1]);

      // -8 shift (log2 domain): keeps e = 2^(d-8) within f16 range; softmax
      // normalization makes the shift exactly cancel.
      #pragma unroll
      for (int t = 0; t < KS; t++) {
        float a = 0.f;
        #pragma unroll
        for (int cP = 0; cP < NCP; cP++)
          a = __builtin_amdgcn_fdot2(qp[cP], srel2[t * 4 + cP], a, false);
        rq[o][t] = a - 8.0f;
      }
    }
  }

  // ---- window loop: logits via ci-packed fdot2; accum via j-packed fdot2 ----
  float s[OW], xa[OW][DH];
  #pragma unroll
  for (int o = 0; o < OW; o++) {
    s[o] = 0.f;
    #pragma unroll
    for (int ci = 0; ci < DH; ci++) xa[o][ci] = 0.f;
  }

#define WINLOOP(DINIT)                                                         \
  _Pragma("unroll")                                                            \
  for (int i = 0; i < KS; i++) {                                               \
    const int row = ty + i;                                                    \
    const int wbase = row * RSTW + 2 * tx;                                     \
    h2v xw[NCP][8];                                                            \
    _Pragma("unroll")                                                          \
    for (int cp = 0; cp < NCP; cp++) {                                         \
      const h4v* bp = (const h4v*)&xs2[cp * PLW + wbase];                      \
      h4v r0 = bp[0], r1 = bp[1], r2 = bp[2], r3 = bp[3];                      \
      xw[cp][0] = __builtin_shufflevector(r0, r0, 0, 1);                       \
      xw[cp][1] = __builtin_shufflevector(r0, r0, 2, 3);                       \
      xw[cp][2] = __builtin_shufflevector(r1, r1, 0, 1);                       \
      xw[cp][3] = __builtin_shufflevector(r1, r1, 2, 3);                       \
      xw[cp][4] = __builtin_shufflevector(r2, r2, 0, 1);                       \
      xw[cp][5] = __builtin_shufflevector(r2, r2, 2, 3);                       \
      xw[cp][6] = __builtin_shufflevector(r3, r3, 0, 1);                       \
      xw[cp][7] = __builtin_shufflevector(r3, r3, 2, 3);                       \
    }                                                                          \
    h2v ep[OW][4];                                                             \
    _Pragma("unroll")                                                          \
    for (int o = 0; o < OW; o++) {                                             \
      float e[KS];                                                             \
      float se = 0.f;                                                          \
      _Pragma("unroll")                                                        \
      for (int j = 0; j < KS; j++) {                                           \
        float d = (DINIT);                                                     \
        _Pragma("unroll")                                                      \
        for (int cp = 0; cp < NCP; cp++)                                       \
          d = __builtin_amdgcn_fdot2(qkh[o][cp], xw[cp][o + j], d, false);     \
        e[j] = EXP2(d);                                                        \
        se += e[j];                                                            \
      }                                                                        \
      s[o] += se;                                                              \
      if (o == 0) {                                                            \
        ep[0][0] = __builtin_amdgcn_cvt_pkrtz(e[0], e[1]);                     \
        ep[0][1] = __builtin_amdgcn_cvt_pkrtz(e[2], e[3]);                     \
        ep[0][2] = __builtin_amdgcn_cvt_pkrtz(e[4], e[5]);                     \
        ep[0][3] = __builtin_amdgcn_cvt_pkrtz(e[6], 0.0f);                     \
      } else {                                                                 \
        ep[1][0] = __builtin_amdgcn_cvt_pkrtz(0.0f, e[0]);                     \
        ep[1][1] = __builtin_amdgcn_cvt_pkrtz(e[1], e[2]);                     \
        ep[1][2] = __builtin_amdgcn_cvt_pkrtz(e[3], e[4]);                     \
        ep[1][3] = __builtin_amdgcn_cvt_pkrtz(e[5], e[6]);                     \
      }                                                                        \
    }                                                                          \
    /* accumulate via j-packed dots: cols (2tx..2tx+7) per channel */          \
    _Pragma("unroll")                                                          \
    for (int ci = 0; ci < DH; ci++) {                                          \
      const h2v* jp = &xs1[ci * PL1 + row * RST1 + tx];                        \
      h2v xj0 = jp[0], xj1 = jp[1], xj2 = jp[2], xj3 = jp[3];                  \
      float a0 = xa[0][ci];                                                    \
      a0 = __builtin_amdgcn_fdot2(ep[0][0], xj0, a0, false);                   \
      a0 = __builtin_amdgcn_fdot2(ep[0][1], xj1, a0, false);                   \
      a0 = __builtin_amdgcn_fdot2(ep[0][2], xj2, a0, false);                   \
      a0 = __builtin_amdgcn_fdot2(ep[0][3], xj3, a0, false);                   \
      xa[0][ci] = a0;                                                          \
      float a1 = xa[1][ci];                                                    \
      a1 = __builtin_amdgcn_fdot2(ep[1][0], xj0, a1, false);                   \
      a1 = __builtin_amdgcn_fdot2(ep[1][1], xj1, a1, false);                   \
      a1 = __builtin_amdgcn_fdot2(ep[1][2], xj2, a1, false);                   \
      a1 = __builtin_amdgcn_fdot2(ep[1][3], xj3, a1, false);                   \
      xa[1][ci] = a1;                                                          \
    }                                                                          \
  }

  if (g < 4) { WINLOOP(rq[o][i]) }
  else       { WINLOOP(rq[o][j]) }
#undef WINLOOP

  // ---- epilogue: out = Wv * (xa / s) via fdot2; float2 stores ----
  h2v xav2[OW][NCP];
  #pragma unroll
  for (int o = 0; o < OW; o++) {
    float inv = 1.0f / s[o];
    #pragma unroll
    for (int cp = 0; cp < NCP; cp++)
      xav2[o][cp] = __builtin_amdgcn_cvt_pkrtz(xa[o][2 * cp] * inv,
                                               xa[o][2 * cp + 1] * inv);
  }

  __builtin_amdgcn_s_setprio(0);

  const int h = h0 + ty;
  const int wbase = w0 + 2 * tx;
  #pragma unroll
  for (int c = 0; c < DH; c++) {
    float a0 = 0.f, a1 = 0.f;
    #pragma unroll
    for (int cp = 0; cp < NCP; cp++) {
      a0 = __builtin_amdgcn_fdot2(swv2[c * 4 + cp], xav2[0][cp], a0, false);
      a1 = __builtin_amdgcn_fdot2(swv2[c * 4 + cp], xav2[1][cp], a1, false);
    }
    *(float2*)(&out[((size_t)(b * CH + g * DH + c) * HH + h) * WW + wbase]) =
        make_float2(a0, a1);
  }
}

extern "C" void kernel_launch(void* const* d_in, const int* in_sizes, int n_in,
                              void* d_out, int out_size, void* d_ws, size_t ws_size,
                              hipStream_t stream) {
  const float* x    = (const float*)d_in[0];
  // d_in[1] = r, unused by the reference computation
  const float* wq   = (const float*)d_in[2];
  const float* wk   = (const float*)d_in[3];
  const float* wv   = (const float*)d_in[4];
  const float* relh = (const float*)d_in[5];
  const float* relw = (const float*)d_in[6];
  float* out = (float*)d_out;

  const int B = in_sizes[0] / (CH * HH * WW);   // 8
  dim3 grid(WW / TW, HH / TH, B * NG);          // 2 x 4 x 64 = 512 blocks
  dim3 block(16, 16, 1);                        // 256 threads = 4 waves
  saconv_kernel<<<grid, block, 0, stream>>>(x, wq, wk, wv, relh, relw, out);
}

// Round 23
// 17.134 us; speedup vs baseline: 1.0588x; 1.0588x over previous
//
#include <hip/hip_runtime.h>
#include <math.h>

#define NG  8
#define DH  8
#define NCP 4     // channel pairs
#define KS  7
#define PAD 3
#define TH  16    // tile rows
#define TW  32    // tile cols
#define OW  2     // outputs per thread along W
#define TPH 22    // padded tile rows
#define RSTW 40   // LDS row stride in h2-words (38 cols + 2 pad)
#define PLW  (TPH * RSTW)   // 880 words per cp-plane
#define CH  64
#define HH  64
#define WW  64

typedef __fp16 h2v __attribute__((ext_vector_type(2)));
typedef __fp16 h4v __attribute__((ext_vector_type(4)));

#if __has_builtin(__builtin_amdgcn_exp2f)
#define EXP2(x) __builtin_amdgcn_exp2f(x)
#else
#define EXP2(x) exp2f(x)
#endif

__device__ __forceinline__ int imin(int a, int b) { return a < b ? a : b; }
__device__ __forceinline__ int imax(int a, int b) { return a > b ? a : b; }

__global__ __launch_bounds__(256, 2)   // cap 128 VGPR (R12-proven)
void saconv_kernel(const float* __restrict__ x,
                   const float* __restrict__ wq,
                   const float* __restrict__ wk,
                   const float* __restrict__ wv,
                   const float* __restrict__ relh,
                   const float* __restrict__ relw,
                   float* __restrict__ out) {
  // xs2[cp*PLW + row*RSTW + col] = h2( x[b,g*8+2cp,row',col'], x[b,g*8+2cp+1,row',col'] )
  __shared__ h2v xs2[NCP * PLW];        // 14.1 KB
  __shared__ h2v swq2[DH * NCP];        // [c][cp]  = (wq[c][2cp], wq[c][2cp+1])
  __shared__ h2v swv2[DH * NCP];        // [c][cp]
  __shared__ h2v swk2[DH * NCP];        // [ci][cP] = sl2e*(wk[2cP][ci], wk[2cP+1][ci]) transposed
  __shared__ h2v srel2[KS * NCP];       // [t][cP]  = sl2e*(rel[2cP][t], rel[2cP+1][t])

  const int tx  = threadIdx.x;          // 0..15 (pair of output columns)
  const int ty  = threadIdx.y;          // 0..15 (output row)
  const int tid = ty * 16 + tx;
  const int bz  = blockIdx.z;
  const int b   = bz >> 3;
  const int g   = bz & 7;
  const int h0  = blockIdx.y * TH;
  const int w0  = blockIdx.x * TW;

  const float sl2e = 0.35355339059327373f * 1.4426950408889634f;  // sqrt(1/8)*log2(e)

  // ---- stage weights as f16 pairs (124 items) ----
  if (tid < 32) {
    int c = tid >> 2, cp = tid & 3;
    swq2[tid] = __builtin_amdgcn_cvt_pkrtz(wq[g * 64 + c * 8 + 2 * cp],
                                           wq[g * 64 + c * 8 + 2 * cp + 1]);
  } else if (tid < 64) {
    int t2 = tid - 32;
    int c = t2 >> 2, cp = t2 & 3;
    swv2[t2] = __builtin_amdgcn_cvt_pkrtz(wv[g * 64 + c * 8 + 2 * cp],
                                          wv[g * 64 + c * 8 + 2 * cp + 1]);
  } else if (tid < 96) {
    int t2 = tid - 64;
    int ci = t2 >> 2, cP = t2 & 3;
    swk2[t2] = __builtin_amdgcn_cvt_pkrtz(wk[g * 64 + (2 * cP) * 8 + ci] * sl2e,
                                          wk[g * 64 + (2 * cP + 1) * 8 + ci] * sl2e);
  } else if (tid < 96 + KS * NCP) {
    int t2 = tid - 96;
    int t = t2 >> 2, cP = t2 & 3;
    float a0, a1;
    if (g < 4) {
      a0 = relh[(g * 8 + 2 * cP) * KS + t];
      a1 = relh[(g * 8 + 2 * cP + 1) * KS + t];
    } else {
      a0 = relw[((g - 4) * 8 + 2 * cP) * KS + t];
      a1 = relw[((g - 4) * 8 + 2 * cP + 1) * KS + t];
    }
    srel2[t2] = __builtin_amdgcn_cvt_pkrtz(a0 * sl2e, a1 * sl2e);
  }

  // ---- stage zero-padded x tile as f16 channel-pairs (b64 = 2 cols) ----
  const float* xb = x + (size_t)(b * CH + g * DH) * (HH * WW);
  const int NCHK = NCP * TPH * 19;      // 1672 b64 chunks (cols 0..37)
  #pragma unroll
  for (int kk = 0; kk < 7; kk++) {
    int f = tid + kk * 256;
    if (f < NCHK) {
      int cp  = f / (TPH * 19);
      int r   = f - cp * (TPH * 19);
      int row = r / 19;
      int cc  = r - row * 19;
      int yy  = h0 + row - PAD;
      int cy  = imin(imax(yy, 0), HH - 1);
      bool yok = (yy >= 0) & (yy < HH);
      const float* p0 = xb + ((size_t)(2 * cp) * HH + cy) * WW;
      float v0[2], v1[2];
      #pragma unroll
      for (int e = 0; e < 2; e++) {
        int xx = w0 + 2 * cc + e - PAD;
        int cx = imin(imax(xx, 0), WW - 1);
        bool inb = yok & (xx >= 0) & (xx < WW);
        float a0 = p0[cx];
        float a1 = p0[HH * WW + cx];
        v0[e] = inb ? a0 : 0.0f;
        v1[e] = inb ? a1 : 0.0f;
      }
      h2v pk0 = __builtin_amdgcn_cvt_pkrtz(v0[0], v1[0]);
      h2v pk1 = __builtin_amdgcn_cvt_pkrtz(v0[1], v1[1]);
      h4v w4 = { pk0.x, pk0.y, pk1.x, pk1.y };
      *(h4v*)&xs2[cp * PLW + row * RSTW + 2 * cc] = w4;
    }
  }
  __syncthreads();

  // ---- T5: boost this block's compute phase over the co-resident block's staging ----
  __builtin_amdgcn_s_setprio(1);

  // ---- preamble, all fdot2 ----
  h2v  qkh[OW][NCP];
  float rq[OW][KS];
  {
    h2v xc2[OW][NCP];
    #pragma unroll
    for (int o = 0; o < OW; o++)
      #pragma unroll
      for (int cp = 0; cp < NCP; cp++)
        xc2[o][cp] = xs2[cp * PLW + (ty + PAD) * RSTW + (2 * tx + o + PAD)];

    #pragma unroll
    for (int o = 0; o < OW; o++) {
      float q_[DH];
      #pragma unroll
      for (int c = 0; c < DH; c++) {
        float a = 0.f;
        #pragma unroll
        for (int cp = 0; cp < NCP; cp++)
          a = __builtin_amdgcn_fdot2(swq2[c * 4 + cp], xc2[o][cp], a, false);
        q_[c] = a;
      }
      h2v qp[NCP];
      #pragma unroll
      for (int cP = 0; cP < NCP; cP++)
        qp[cP] = __builtin_amdgcn_cvt_pkrtz(q_[2 * cP], q_[2 * cP + 1]);

      float qkt[DH];
      #pragma unroll
      for (int ci = 0; ci < DH; ci++) {
        float a = 0.f;
        #pragma unroll
        for (int cP = 0; cP < NCP; cP++)
          a = __builtin_amdgcn_fdot2(qp[cP], swk2[ci * 4 + cP], a, false);
        qkt[ci] = a;
      }
      #pragma unroll
      for (int cp = 0; cp < NCP; cp++)
        qkh[o][cp] = __builtin_amdgcn_cvt_pkrtz(qkt[2 * cp], qkt[2 * cp + 1]);

      #pragma unroll
      for (int t = 0; t < KS; t++) {
        float a = 0.f;
        #pragma unroll
        for (int cP = 0; cP < NCP; cP++)
          a = __builtin_amdgcn_fdot2(qp[cP], srel2[t * 4 + cP], a, false);
        rq[o][t] = a;
      }
    }
  }

  // ---- window loop ----
  float s[OW], xa[OW][DH];
  #pragma unroll
  for (int o = 0; o < OW; o++) {
    s[o] = 0.f;
    #pragma unroll
    for (int ci = 0; ci < DH; ci++) xa[o][ci] = 0.f;
  }

#define WINLOOP(DINIT)                                                         \
  _Pragma("unroll")                                                            \
  for (int i = 0; i < KS; i++) {                                               \
    const int wbase = (ty + i) * RSTW + 2 * tx;                                \
    h2v xw[NCP][8];                                                            \
    _Pragma("unroll")                                                          \
    for (int cp = 0; cp < NCP; cp++) {                                         \
      const h4v* bp = (const h4v*)&xs2[cp * PLW + wbase];                      \
      h4v r0 = bp[0], r1 = bp[1], r2 = bp[2], r3 = bp[3];                      \
      xw[cp][0] = __builtin_shufflevector(r0, r0, 0, 1);                       \
      xw[cp][1] = __builtin_shufflevector(r0, r0, 2, 3);                       \
      xw[cp][2] = __builtin_shufflevector(r1, r1, 0, 1);                       \
      xw[cp][3] = __builtin_shufflevector(r1, r1, 2, 3);                       \
      xw[cp][4] = __builtin_shufflevector(r2, r2, 0, 1);                       \
      xw[cp][5] = __builtin_shufflevector(r2, r2, 2, 3);                       \
      xw[cp][6] = __builtin_shufflevector(r3, r3, 0, 1);                       \
      xw[cp][7] = __builtin_shufflevector(r3, r3, 2, 3);                       \
    }                                                                          \
    _Pragma("unroll")                                                          \
    for (int o = 0; o < OW; o++) {                                             \
      float e[KS];                                                             \
      float se = 0.f;                                                          \
      _Pragma("unroll")                                                        \
      for (int j = 0; j < KS; j++) {                                           \
        float d = (DINIT);                                                     \
        _Pragma("unroll")                                                      \
        for (int cp = 0; cp < NCP; cp++)                                       \
          d = __builtin_amdgcn_fdot2(qkh[o][cp], xw[cp][o + j], d, false);     \
        e[j] = EXP2(d);                                                        \
        se += e[j];                                                            \
      }                                                                        \
      s[o] += se;                                                              \
      _Pragma("unroll")                                                        \
      for (int cp = 0; cp < NCP; cp++) {                                       \
        float a0 = xa[o][2 * cp];                                              \
        float a1 = xa[o][2 * cp + 1];                                          \
        _Pragma("unroll")                                                      \
        for (int j = 0; j < KS; j++) {                                         \
          a0 = fmaf(e[j], (float)xw[cp][o + j].x, a0);                         \
          a1 = fmaf(e[j], (float)xw[cp][o + j].y, a1);                         \
        }                                                                      \
        xa[o][2 * cp]     = a0;                                                \
        xa[o][2 * cp + 1] = a1;                                                \
      }                                                                        \
    }                                                                          \
  }

  if (g < 4) { WINLOOP(rq[o][i]) }
  else       { WINLOOP(rq[o][j]) }
#undef WINLOOP

  // ---- epilogue: out = Wv * (xa / s) via fdot2 ----
  h2v xav2[OW][NCP];
  #pragma unroll
  for (int o = 0; o < OW; o++) {
    float inv = 1.0f / s[o];
    #pragma unroll
    for (int cp = 0; cp < NCP; cp++)
      xav2[o][cp] = __builtin_amdgcn_cvt_pkrtz(xa[o][2 * cp] * inv,
                                               xa[o][2 * cp + 1] * inv);
  }

  __builtin_amdgcn_s_setprio(0);   // drop priority before the store/drain phase

  const int h = h0 + ty;
  const int wbase = w0 + 2 * tx;
  #pragma unroll
  for (int c = 0; c < DH; c++) {
    float a0 = 0.f, a1 = 0.f;
    #pragma unroll
    for (int cp = 0; cp < NCP; cp++) {
      a0 = __builtin_amdgcn_fdot2(swv2[c * 4 + cp], xav2[0][cp], a0, false);
      a1 = __builtin_amdgcn_fdot2(swv2[c * 4 + cp], xav2[1][cp], a1, false);
    }
    *(float2*)(&out[((size_t)(b * CH + g * DH + c) * HH + h) * WW + wbase]) =
        make_float2(a0, a1);
  }
}

extern "C" void kernel_launch(void* const* d_in, const int* in_sizes, int n_in,
                              void* d_out, int out_size, void* d_ws, size_t ws_size,
                              hipStream_t stream) {
  const float* x    = (const float*)d_in[0];
  // d_in[1] = r, unused by the reference computation
  const float* wq   = (const float*)d_in[2];
  const float* wk   = (const float*)d_in[3];
  const float* wv   = (const float*)d_in[4];
  const float* relh = (const float*)d_in[5];
  const float* relw = (const float*)d_in[6];
  float* out = (float*)d_out;

  const int B = in_sizes[0] / (CH * HH * WW);   // 8
  dim3 grid(WW / TW, HH / TH, B * NG);          // 2 x 4 x 64 = 512 blocks
  dim3 block(16, 16, 1);                        // 256 threads = 4 waves
  saconv_kernel<<<grid, block, 0, stream>>>(x, wq, wk, wv, relh, relw, out);
}